// Round 1
// baseline (392.998 us; speedup 1.0000x reference)
//
#include <hip/hip_runtime.h>
#include <hip/hip_bf16.h>
#include <hip/hip_fp16.h>

typedef __attribute__((ext_vector_type(8))) short short8;
typedef __attribute__((ext_vector_type(4))) float f32x4;

#define DEVI __device__ __forceinline__

DEVI unsigned short f2bf(float f){
  __hip_bfloat16 h = __float2bfloat16(f);
  unsigned short u; __builtin_memcpy(&u, &h, 2); return u;
}

// ---------------- cast fp32 -> bf16 (vectorized float4 -> ushort4) ----------------
__global__ void cast_f32_bf16(const float* __restrict__ in, unsigned short* __restrict__ out, int n4){
  int stride = gridDim.x * blockDim.x;
  for (int i = blockIdx.x*blockDim.x + threadIdx.x; i < n4; i += stride){
    float4 f = reinterpret_cast<const float4*>(in)[i];
    ushort4 o;
    o.x = f2bf(f.x); o.y = f2bf(f.y); o.z = f2bf(f.z); o.w = f2bf(f.w);
    reinterpret_cast<ushort4*>(out)[i] = o;
  }
}

// ---------------- transpose + cast: WT[n][k] = W[k][n] ----------------
__global__ void transpose_cast_w(const float* __restrict__ W, unsigned short* __restrict__ WT, int K, int N){
  __shared__ float tile[32][33];
  int bn = blockIdx.x*32, bk = blockIdx.y*32;
  int tx = threadIdx.x & 31, ty = threadIdx.x >> 5;
  for (int r=0;r<32;r+=8)
    tile[ty+r][tx] = W[(long)(bk+ty+r)*N + bn+tx];
  __syncthreads();
  for (int r=0;r<32;r+=8)
    WT[(long)(bn+ty+r)*K + bk+tx] = (short)f2bf(tile[tx][ty+r]);
}

// ---------------- async global->LDS staging, 16B per lane ----------------
DEVI void stage16(const short* gsrc, short* lbase, int lane){
#if __has_builtin(__builtin_amdgcn_global_load_lds)
  __builtin_amdgcn_global_load_lds(
      (const __attribute__((address_space(1))) unsigned int*)gsrc,
      (__attribute__((address_space(3))) unsigned int*)lbase, 16, 0, 0);
#else
  reinterpret_cast<short8*>(lbase + lane*8)[0] = *reinterpret_cast<const short8*>(gsrc);
#endif
}

// ---------------- GEMM: C[M,N] = scale * (A[M,K] @ Bt[N,K]^T) + bias ----------------
// OT: 0=f32, 1=f16, 2=bf16.  BIAS: 0 none, 1 per-col, 2 per-row.
// 128x128 tile, BK=32, 256 threads (4 waves, 2x2), mfma_f32_16x16x32_bf16.
template<int OT, int BIAS>
__global__ __launch_bounds__(256, 2)
void gemm_bt(const short* __restrict__ A, const short* __restrict__ Bt,
             const float* __restrict__ bias, void* __restrict__ Cv,
             int M, int N, int K, long sA, long sB, long sC, float scale)
{
  __shared__ short smem[8192];   // A tile [0,4096) elems, B tile [4096,8192)
  const long bz = blockIdx.z;
  A  += bz * sA;
  Bt += bz * sB;
  const int m0 = blockIdx.x * 128, n0 = blockIdx.y * 128;
  const int t = threadIdx.x, lane = t & 63, w = t >> 6;
  const int wr = w >> 1, wc = w & 1;
  const int la = lane & 15, hk = (lane >> 4) * 8;
  const int aOff = (wr*64 + la)*32 + hk;
  const int bOff = 4096 + (wc*64 + la)*32 + hk;

  // staging: 16 chunks of 1KB (8 A + 8 B); wave w owns chunks w*4..w*4+3
  const short* srcp[4];
  int loff[4];
  #pragma unroll
  for (int i=0;i<4;i++){
    int ch = w*4 + i;
    int half = ch >> 3, c = ch & 7;
    int row = c*16 + (lane >> 2), col = (lane & 3) * 8;
    srcp[i] = (half ? Bt + (long)(n0 + row)*K : A + (long)(m0 + row)*K) + col;
    loff[i] = ch * 512;
  }

  f32x4 acc[4][4] = {};
  const int nk = K >> 5;
  for (int kt = 0; kt < nk; ++kt){
    #pragma unroll
    for (int i=0;i<4;i++) stage16(srcp[i], &smem[loff[i]], lane);
    __syncthreads();
    short8 a[4], b[4];
    #pragma unroll
    for (int m=0;m<4;m++) a[m] = *reinterpret_cast<const short8*>(&smem[aOff + m*512]);
    #pragma unroll
    for (int n=0;n<4;n++) b[n] = *reinterpret_cast<const short8*>(&smem[bOff + n*512]);
    #pragma unroll
    for (int m=0;m<4;m++)
      #pragma unroll
      for (int n=0;n<4;n++)
        acc[m][n] = __builtin_amdgcn_mfma_f32_16x16x32_bf16(a[m], b[n], acc[m][n], 0, 0, 0);
    __syncthreads();
    #pragma unroll
    for (int i=0;i<4;i++) srcp[i] += 32;
  }

  // epilogue: C/D layout col=lane&15, row=(lane>>4)*4+j  [verified m89]
  const int rowb = m0 + wr*64 + (lane>>4)*4;
  const int colb = n0 + wc*64 + la;
  #pragma unroll
  for (int m=0;m<4;m++){
    #pragma unroll
    for (int n=0;n<4;n++){
      const int col = colb + n*16;
      float badd = (BIAS==1) ? bias[col] : 0.0f;
      #pragma unroll
      for (int j=0;j<4;j++){
        const int row = rowb + m*16 + j;
        float v = acc[m][n][j] * scale + badd;
        if (BIAS==2) v += bias[row];
        const long idx = bz*sC + (long)row*N + col;
        if constexpr (OT==0) ((float*)Cv)[idx] = v;
        else if constexpr (OT==1) ((__half*)Cv)[idx] = __float2half(v);
        else ((unsigned short*)Cv)[idx] = f2bf(v);
      }
    }
  }
}

// ---------------- row softmax, fp16 in -> bf16 out, in place ----------------
// one block (256 thr) per row of 2048
__global__ void softmax_rows(unsigned short* __restrict__ SP, int cols){
  const long row = blockIdx.x;
  unsigned short* rp = SP + row * cols;
  const int t = threadIdx.x, lane = t & 63, w = t >> 6;
  short8 raw = *reinterpret_cast<const short8*>(rp + t*8);
  float v[8];
  #pragma unroll
  for (int i=0;i<8;i++){
    unsigned short us = (unsigned short)raw[i];
    __half h; __builtin_memcpy(&h, &us, 2);
    v[i] = __half2float(h);
  }
  float m = v[0];
  #pragma unroll
  for (int i=1;i<8;i++) m = fmaxf(m, v[i]);
  #pragma unroll
  for (int o=32;o;o>>=1) m = fmaxf(m, __shfl_down(m, o));
  __shared__ float red[8];
  if (lane==0) red[w] = m;
  __syncthreads();
  if (t==0) red[4] = fmaxf(fmaxf(red[0],red[1]), fmaxf(red[2],red[3]));
  __syncthreads();
  const float rowmax = red[4];
  float s = 0.f;
  #pragma unroll
  for (int i=0;i<8;i++){ v[i] = __expf(v[i]-rowmax); s += v[i]; }
  #pragma unroll
  for (int o=32;o;o>>=1) s += __shfl_down(s, o);
  if (lane==0) red[w] = s;
  __syncthreads();
  if (t==0) red[5] = red[0]+red[1]+red[2]+red[3];
  __syncthreads();
  const float inv = 1.0f / red[5];
  short8 outp;
  #pragma unroll
  for (int i=0;i<8;i++) outp[i] = (short)f2bf(v[i]*inv);
  *reinterpret_cast<short8*>(rp + t*8) = outp;
}

extern "C" void kernel_launch(void* const* d_in, const int* in_sizes, int n_in,
                              void* d_out, int out_size, void* d_ws, size_t ws_size,
                              hipStream_t stream)
{
  const int B = 8, S = 2048, D = 1024;
  const int BS = B * S;                      // 16384
  const float* x1 = (const float*)d_in[0];
  const float* x2 = (const float*)d_in[1];
  const float* Wq = (const float*)d_in[2];
  const float* bq = (const float*)d_in[3];
  const float* Wk = (const float*)d_in[4];
  const float* bk = (const float*)d_in[5];
  const float* Wv = (const float*)d_in[6];
  const float* bv = (const float*)d_in[7];

  char* ws = (char*)d_ws;
  const size_t MB = 1024*1024;
  short*          x1b = (short*)(ws);             // 32MB  (dead after q GEMM)
  short*          x2b = (short*)(ws + 32*MB);     // 32MB  (dead after vT GEMM)
  unsigned short* Sc  = (unsigned short*)ws;      // 64MB scores/probs (reuses x1b/x2b region)
  short*          q   = (short*)(ws + 64*MB);     // 32MB
  short*          k   = (short*)(ws + 96*MB);     // 32MB
  short*          vT  = (short*)(ws + 128*MB);    // 32MB  [B][D][S]
  short*          WqT = (short*)(ws + 160*MB);    // 2MB each
  short*          WkT = (short*)(ws + 162*MB);
  short*          WvT = (short*)(ws + 164*MB);    // total 166MB

  cast_f32_bf16<<<4096,256,0,stream>>>(x1, (unsigned short*)x1b, BS*D/4);
  cast_f32_bf16<<<4096,256,0,stream>>>(x2, (unsigned short*)x2b, BS*D/4);
  transpose_cast_w<<<dim3(32,32),256,0,stream>>>(Wq, (unsigned short*)WqT, D, D);
  transpose_cast_w<<<dim3(32,32),256,0,stream>>>(Wk, (unsigned short*)WkT, D, D);
  transpose_cast_w<<<dim3(32,32),256,0,stream>>>(Wv, (unsigned short*)WvT, D, D);

  // k2 = x2 @ Wk + bk (bf16)
  gemm_bt<2,1><<<dim3(BS/128, D/128, 1),256,0,stream>>>(x2b, WkT, bk, k, BS, D, D, 0,0,0, 1.0f);
  // vT[b] = WvT @ x2[b]^T + bv(per-row)  -> [B][D][S]
  gemm_bt<2,2><<<dim3(D/128, S/128, B),256,0,stream>>>(WvT, x2b, bv, vT, D, S, D,
                                                       0, (long)S*D, (long)D*S, 1.0f);
  // q1 = x1 @ Wq + bq (bf16)
  gemm_bt<2,1><<<dim3(BS/128, D/128, 1),256,0,stream>>>(x1b, WqT, bq, q, BS, D, D, 0,0,0, 1.0f);
  // scores = q k^T / sqrt(D) (fp16) — overwrites x1b/x2b region
  gemm_bt<1,0><<<dim3(S/128, S/128, B),256,0,stream>>>(q, k, nullptr, Sc, S, S, D,
                                                       (long)S*D, (long)S*D, (long)S*S, 0.03125f);
  // softmax rows, in place -> bf16 probs
  softmax_rows<<<BS,256,0,stream>>>(Sc, S);
  // O = P @ V : A = P [S,S] bf16, Bt = vT [D,S], C = f32 out
  gemm_bt<0,0><<<dim3(S/128, D/128, B),256,0,stream>>>((short*)Sc, vT, nullptr, d_out, S, D, S,
                                                       (long)S*S, (long)D*S, (long)S*D, 1.0f);
}

// Round 2
// 332.040 us; speedup vs baseline: 1.1836x; 1.1836x over previous
//
#include <hip/hip_runtime.h>
#include <hip/hip_bf16.h>
#include <hip/hip_fp16.h>

typedef __attribute__((ext_vector_type(8))) short short8;
typedef __attribute__((ext_vector_type(4))) float f32x4;

#define DEVI __device__ __forceinline__

DEVI unsigned short f2bf(float f){
  __hip_bfloat16 h = __float2bfloat16(f);
  unsigned short u; __builtin_memcpy(&u, &h, 2); return u;
}

// ---------------- cast fp32 -> bf16 ----------------
__global__ void cast_f32_bf16(const float* __restrict__ in, unsigned short* __restrict__ out, int n4){
  int stride = gridDim.x * blockDim.x;
  for (int i = blockIdx.x*blockDim.x + threadIdx.x; i < n4; i += stride){
    float4 f = reinterpret_cast<const float4*>(in)[i];
    ushort4 o;
    o.x = f2bf(f.x); o.y = f2bf(f.y); o.z = f2bf(f.z); o.w = f2bf(f.w);
    reinterpret_cast<ushort4*>(out)[i] = o;
  }
}

// ---------------- transpose + cast: WT[n][k] = W[k][n] ----------------
__global__ void transpose_cast_w(const float* __restrict__ W, unsigned short* __restrict__ WT, int K, int N){
  __shared__ float tile[32][33];
  int bn = blockIdx.x*32, bk = blockIdx.y*32;
  int tx = threadIdx.x & 31, ty = threadIdx.x >> 5;
  for (int r=0;r<32;r+=8)
    tile[ty+r][tx] = W[(long)(bk+ty+r)*N + bn+tx];
  __syncthreads();
  for (int r=0;r<32;r+=8)
    WT[(long)(bn+ty+r)*K + bk+tx] = (short)f2bf(tile[tx][ty+r]);
}

// ---------------- async global->LDS, 16B/lane ----------------
DEVI void stage16(const short* gsrc, short* lbase){
  __builtin_amdgcn_global_load_lds(
      (const __attribute__((address_space(1))) unsigned int*)gsrc,
      (__attribute__((address_space(3))) unsigned int*)lbase, 16, 0, 0);
}

// Stage one 16KB K-half block (256 rows x 32 k-elems bf16) into LDS.
// Physical LDS is linear (base + lane*16 per chunk); the GLOBAL source per
// lane is pre-swizzled with the st_16x32 involution (byte ^= bit9<<5) so the
// swizzled ds_reads see the right data (rule #21: both-sides-or-neither).
DEVI void stage_half(const short* __restrict__ gtile, int ldK, int koff,
                     short* lds_block, int w, int lane){
  const int r  = lane >> 2;                                   // row in 16-row group
  const int kk = ((lane & 3) * 8) ^ ((lane >= 32) ? 16 : 0);  // pre-swizzled k (elems)
  #pragma unroll
  for (int i = 0; i < 2; ++i){
    const int c = i*8 + w;                                    // chunk 0..15 (16 rows)
    const short* src = gtile + (long)(c*16 + r) * ldK + koff + kk;
    stage16(src, lds_block + c*512);
  }
}

// Swizzled ds_read_b128 of one MFMA fragment from a [16rows][32kelems]-subtiled
// 16KB block; phys = logical ^ ((row&15)>=8 ? 32 : 0)  (st_16x32, ~4-way banks).
DEVI short8 ldsRd(const short* lds, int blk, int rowblk, int lane){
  const int la = lane & 15;
  int q = rowblk*1024 + la*64 + ((lane>>4)<<4);
  q ^= (la >= 8) ? 32 : 0;
  return *reinterpret_cast<const short8*>(lds + blk*8192 + (q>>1));
}

// ---------------- 256x256 8-phase GEMM: C = scale*(A @ Bt^T) + bias ----------
// OT: 0=f32, 1=f16, 2=bf16.  BIAS: 0 none, 1 per-col, 2 per-row.
// BK=64 (2 K-halves), 512 thr = 8 waves (2M x 4N), dbuf LDS 128KB.
// LDS block idx = buf*4 + op*2 + khalf (op 0=A,1=B), 16KB (8192 shorts) each.
template<int OT, int BIAS>
__global__ __launch_bounds__(512, 2)
void gemm8(const short* __restrict__ A, const short* __restrict__ Bt,
           const float* __restrict__ bias, void* __restrict__ Cv,
           int N, int K, long sA, long sB, long sC, float scale, int nx, int ny)
{
  extern __shared__ short lds[];
  // bijective XCD swizzle (all launches have nwg % 8 == 0)
  const int nwg = gridDim.x;
  const int cpx = nwg >> 3;
  const int wg  = (blockIdx.x & 7)*cpx + (blockIdx.x >> 3);
  const int bx  = wg % nx;
  const int tmp = wg / nx;
  const int by  = tmp % ny;
  const long bz = tmp / ny;
  A  += bz * sA;
  Bt += bz * sB;
  const int m0 = bx * 256, n0 = by * 256;
  const short* Ab = A  + (long)m0 * K;
  const short* Bb = Bt + (long)n0 * K;

  const int t = threadIdx.x, lane = t & 63, w = t >> 6;
  const int wr = w >> 2, wc = w & 3;            // 2M x 4N wave grid

  f32x4 acc[8][4] = {};
  short8 bv[4];

  const int NT = K >> 6;          // K-tiles of 64
  const int niter = NT >> 1;      // 2 K-tiles per iteration

  // ---- prologue: tile0 -> buf0 (A.k0,B.k0,A.k1,B.k1), tile1 k0 -> buf1 ----
  stage_half(Ab, K, 0,  lds + 0,     w, lane);
  stage_half(Bb, K, 0,  lds + 16384, w, lane);
  stage_half(Ab, K, 32, lds + 8192,  w, lane);
  stage_half(Bb, K, 32, lds + 24576, w, lane);
  stage_half(Ab, K, 64, lds + 32768, w, lane);
  stage_half(Bb, K, 64, lds + 49152, w, lane);
  asm volatile("s_waitcnt vmcnt(4)" ::: "memory");   // buf0 fully landed
  __builtin_amdgcn_s_barrier();

#define PH(CBUF, QM, QK, SPTR, SKOFF, SBLK, TAILVM) do {                        \
    short8 a0_ = ldsRd(lds, (CBUF)*4 + (QK), wr*8 + (QM)*4 + 0, lane);          \
    short8 a1_ = ldsRd(lds, (CBUF)*4 + (QK), wr*8 + (QM)*4 + 1, lane);          \
    short8 a2_ = ldsRd(lds, (CBUF)*4 + (QK), wr*8 + (QM)*4 + 2, lane);          \
    short8 a3_ = ldsRd(lds, (CBUF)*4 + (QK), wr*8 + (QM)*4 + 3, lane);          \
    if ((QM) == 0){                                                             \
      bv[0] = ldsRd(lds, (CBUF)*4 + 2 + (QK), wc*4 + 0, lane);                  \
      bv[1] = ldsRd(lds, (CBUF)*4 + 2 + (QK), wc*4 + 1, lane);                  \
      bv[2] = ldsRd(lds, (CBUF)*4 + 2 + (QK), wc*4 + 2, lane);                  \
      bv[3] = ldsRd(lds, (CBUF)*4 + 2 + (QK), wc*4 + 3, lane);                  \
    }                                                                           \
    stage_half(SPTR, K, (SKOFF), lds + (SBLK), w, lane);                        \
    __builtin_amdgcn_s_barrier();                                               \
    asm volatile("s_waitcnt lgkmcnt(0)" ::: "memory");                          \
    __builtin_amdgcn_s_setprio(1);                                              \
    { short8 av_[4] = {a0_, a1_, a2_, a3_};                                     \
      _Pragma("unroll")                                                         \
      for (int i_=0;i_<4;i_++){                                                 \
        _Pragma("unroll")                                                       \
        for (int j_=0;j_<4;j_++)                                                \
          acc[(QM)*4+i_][j_] = __builtin_amdgcn_mfma_f32_16x16x32_bf16(         \
              av_[i_], bv[j_], acc[(QM)*4+i_][j_], 0, 0, 0);                    \
      }                                                                         \
    }                                                                           \
    __builtin_amdgcn_s_setprio(0);                                              \
    if (TAILVM) asm volatile("s_waitcnt vmcnt(4)" ::: "memory");                \
    __builtin_amdgcn_s_barrier();                                               \
  } while(0)

  for (int it = 0; it < niter; ++it){
    const int u  = it*2;
    const int k1 = ((u+1) % NT)*64;   // tile u+1 (buf1)
    const int k2 = ((u+2) % NT)*64;   // tile u+2 (buf0) — wraps harmlessly at tail
    const int k3 = ((u+3) % NT)*64;   // tile u+3 (buf1)
    // compute tile u (buf0)
    PH(0, 0, 0, Ab, k1+32, 40960, 0);   // stage buf1.A.k1 (u+1)
    PH(0, 1, 0, Bb, k1+32, 57344, 0);   // stage buf1.B.k1 (u+1)
    PH(0, 0, 1, Ab, k2,    0,     0);   // stage buf0.A.k0 (u+2)
    PH(0, 1, 1, Bb, k2,    16384, 1);   // stage buf0.B.k0 (u+2); vmcnt(4)
    // compute tile u+1 (buf1)
    PH(1, 0, 0, Ab, k2+32, 8192,  0);   // stage buf0.A.k1 (u+2)
    PH(1, 1, 0, Bb, k2+32, 24576, 0);   // stage buf0.B.k1 (u+2)
    PH(1, 0, 1, Ab, k3,    32768, 0);   // stage buf1.A.k0 (u+3)
    PH(1, 1, 1, Bb, k3,    49152, 1);   // stage buf1.B.k0 (u+3); vmcnt(4)
  }
#undef PH

  // ---- epilogue: C/D layout col=lane&15, row=(lane>>4)*4+j ----
  const int rowb = m0 + wr*128 + ((lane>>4)<<2);
  const int colb = n0 + wc*64 + (lane & 15);
  #pragma unroll
  for (int mi=0; mi<8; ++mi){
    #pragma unroll
    for (int nj=0; nj<4; ++nj){
      const int col = colb + nj*16;
      float badd = (BIAS==1) ? bias[col] : 0.0f;
      #pragma unroll
      for (int j=0;j<4;j++){
        const int row = rowb + mi*16 + j;
        float v = acc[mi][nj][j] * scale + badd;
        if (BIAS==2) v += bias[row];
        const long idx = bz*sC + (long)row*N + col;
        if constexpr (OT==0) ((float*)Cv)[idx] = v;
        else if constexpr (OT==1) ((__half*)Cv)[idx] = __float2half(v);
        else ((unsigned short*)Cv)[idx] = f2bf(v);
      }
    }
  }
}

// ---------------- row softmax, fp16 in -> bf16 out, in place ----------------
__global__ void softmax_rows(unsigned short* __restrict__ SP, int cols){
  const long row = blockIdx.x;
  unsigned short* rp = SP + row * cols;
  const int t = threadIdx.x, lane = t & 63, w = t >> 6;
  short8 raw = *reinterpret_cast<const short8*>(rp + t*8);
  float v[8];
  #pragma unroll
  for (int i=0;i<8;i++){
    unsigned short us = (unsigned short)raw[i];
    __half h; __builtin_memcpy(&h, &us, 2);
    v[i] = __half2float(h);
  }
  float m = v[0];
  #pragma unroll
  for (int i=1;i<8;i++) m = fmaxf(m, v[i]);
  #pragma unroll
  for (int o=32;o;o>>=1) m = fmaxf(m, __shfl_down(m, o));
  __shared__ float red[8];
  if (lane==0) red[w] = m;
  __syncthreads();
  if (t==0) red[4] = fmaxf(fmaxf(red[0],red[1]), fmaxf(red[2],red[3]));
  __syncthreads();
  const float rowmax = red[4];
  float s = 0.f;
  #pragma unroll
  for (int i=0;i<8;i++){ v[i] = __expf(v[i]-rowmax); s += v[i]; }
  #pragma unroll
  for (int o=32;o;o>>=1) s += __shfl_down(s, o);
  if (lane==0) red[w] = s;
  __syncthreads();
  if (t==0) red[5] = red[0]+red[1]+red[2]+red[3];
  __syncthreads();
  const float inv = 1.0f / red[5];
  short8 outp;
  #pragma unroll
  for (int i=0;i<8;i++) outp[i] = (short)f2bf(v[i]*inv);
  *reinterpret_cast<short8*>(rp + t*8) = outp;
}

extern "C" void kernel_launch(void* const* d_in, const int* in_sizes, int n_in,
                              void* d_out, int out_size, void* d_ws, size_t ws_size,
                              hipStream_t stream)
{
  const int B = 8, S = 2048, D = 1024;
  const int BS = B * S;                      // 16384
  const float* x1 = (const float*)d_in[0];
  const float* x2 = (const float*)d_in[1];
  const float* Wq = (const float*)d_in[2];
  const float* bq = (const float*)d_in[3];
  const float* Wk = (const float*)d_in[4];
  const float* bk = (const float*)d_in[5];
  const float* Wv = (const float*)d_in[6];
  const float* bv = (const float*)d_in[7];

  char* ws = (char*)d_ws;
  const size_t MB = 1024*1024;
  short*          x1b = (short*)(ws);             // 32MB (dead after q GEMM)
  short*          x2b = (short*)(ws + 32*MB);     // 32MB (dead after vT GEMM)
  unsigned short* Sc  = (unsigned short*)ws;      // 64MB scores/probs (reuses x1b/x2b)
  short*          q   = (short*)(ws + 64*MB);     // 32MB
  short*          k   = (short*)(ws + 96*MB);     // 32MB
  short*          vT  = (short*)(ws + 128*MB);    // 32MB [B][D][S]
  short*          WqT = (short*)(ws + 160*MB);
  short*          WkT = (short*)(ws + 162*MB);
  short*          WvT = (short*)(ws + 164*MB);    // total 166MB

  const size_t SH = 131072;  // 128KB dynamic LDS

  cast_f32_bf16<<<4096,256,0,stream>>>(x1, (unsigned short*)x1b, BS*D/4);
  cast_f32_bf16<<<4096,256,0,stream>>>(x2, (unsigned short*)x2b, BS*D/4);
  transpose_cast_w<<<dim3(32,32),256,0,stream>>>(Wq, (unsigned short*)WqT, D, D);
  transpose_cast_w<<<dim3(32,32),256,0,stream>>>(Wk, (unsigned short*)WkT, D, D);
  transpose_cast_w<<<dim3(32,32),256,0,stream>>>(Wv, (unsigned short*)WvT, D, D);

  // k2 = x2 @ Wk + bk (bf16): M=BS,N=D,K=D; grid 64x4 = 256
  gemm8<2,1><<<256, 512, SH, stream>>>(x2b, WkT, bk, k, D, D, 0,0,0, 1.0f, 64, 4);
  // vT[b] = WvT @ x2[b]^T + bv(per-row): M=D,N=S,K=D; grid 4x8x8 = 256
  gemm8<2,2><<<256, 512, SH, stream>>>(WvT, x2b, bv, vT, S, D, 0, (long)S*D, (long)D*S, 1.0f, 4, 8);
  // q1 = x1 @ Wq + bq: grid 256
  gemm8<2,1><<<256, 512, SH, stream>>>(x1b, WqT, bq, q, D, D, 0,0,0, 1.0f, 64, 4);
  // scores = q k^T / 32 (fp16): M=S,N=S,K=D; grid 8x8x8 = 512
  gemm8<1,0><<<512, 512, SH, stream>>>(q, k, nullptr, Sc, S, D,
                                       (long)S*D, (long)S*D, (long)S*S, 0.03125f, 8, 8);
  // softmax rows, in place -> bf16 probs
  softmax_rows<<<BS,256,0,stream>>>(Sc, S);
  // O = P @ V: A=P[S,S] bf16, Bt=vT[D,S], C=f32 out: M=S,N=D,K=S; grid 8x4x8 = 256
  gemm8<0,0><<<256, 512, SH, stream>>>((short*)Sc, vT, nullptr, d_out, D, S,
                                       (long)S*S, (long)D*S, (long)S*D, 1.0f, 8, 4);
}